// Round 5
// baseline (264.215 us; speedup 1.0000x reference)
//
#include <hip/hip_runtime.h>
#include <hip/hip_bf16.h>

// SequentialEdge: B=256, R=256, A=8, D=2.
// Output: 5 chunks (i=-2..2), chunk i = B*(R-|i|)*64 rows of [node_in, node_out, i+2],
// -1 rows where chain differs; trailing scalar 5. Total ints = 62,619,648 (+1).
//
// R5 design: one thread per edge-quad (4 edges, one residue pair -> ONE decode +
// ONE chain compare per 48B). Direct stride-48 dwordx4 stores (int4 indices
// 3t, 3t+1, 3t+2): no LDS, no barrier. Each 128B line is fully dirtied within
// 3 consecutive wave-stores -> L2 write-combines to full-line DRAM writes.
// (R4's nt-store hint regressed ~4us; reverted to regular stores.)
//
// Chunk table (edge starts): 0 / 4,161,536 / 8,339,456 / 12,533,760 / 16,711,680
// per-graph edges: 16256 / 16320 / 16384 / 16320 / 16256. E_TOTAL = 20,873,216.

#define E_TOTAL   20873216u
#define INT_TOTAL 62619648u

typedef int v4i __attribute__((ext_vector_type(4)));

__global__ __launch_bounds__(256)
void seqedge_kernel(const int* __restrict__ chain, int* __restrict__ out) {
    const unsigned gid = blockIdx.x * 256u + threadIdx.x;
    const unsigned e0  = gid * 4u;            // first edge of this thread's quad

    // ---- chunk decode (once per 4 edges) ----
    unsigned g, rem; int i, lo, rel;
    if (e0 < 4161536u)       { g = e0 / 16256u;                    rem = e0 - g * 16256u; i = -2; lo = 2; rel = 0; }
    else if (e0 < 8339456u)  { unsigned eo = e0 - 4161536u;  g = eo / 16320u; rem = eo - g * 16320u; i = -1; lo = 1; rel = 1; }
    else if (e0 < 12533760u) { unsigned eo = e0 - 8339456u;  g = eo >> 14;    rem = eo & 16383u;     i = 0;  lo = 0; rel = 2; }
    else if (e0 < 16711680u) { unsigned eo = e0 - 12533760u; g = eo / 16320u; rem = eo - g * 16320u; i = 1;  lo = 0; rel = 3; }
    else                     { unsigned eo = e0 - 16711680u; g = eo / 16256u; rem = eo - g * 16256u; i = 2;  lo = 0; rel = 4; }

    const unsigned rl  = (rem >> 6) + (unsigned)lo;  // local residue
    const unsigned ai  = (rem >> 3) & 7u;            // in-atom (same for all 4 edges)
    const unsigned ao0 = rem & 7u;                   // 0 or 4 (quad is 4-aligned)
    const int res_in  = (int)(g * 256u + rl);
    const int res_out = res_in + i;
    const bool same = chain[res_in] == chain[res_out];

    const int x  = same ? res_in * 8 + (int)ai : -1;
    const int r  = same ? rel : -1;
    const int yb = res_out * 8 + (int)ao0;
    const int y0 = same ? yb     : -1;
    const int y1 = same ? yb + 1 : -1;
    const int y2 = same ? yb + 2 : -1;
    const int y3 = same ? yb + 3 : -1;

    // ---- direct write: 12 ints = 3 int4 at indices 3*gid .. 3*gid+2 ----
    v4i* outv = reinterpret_cast<v4i*>(out) + 3u * gid;
    outv[0] = (v4i){x,  y0, r,  x};
    outv[1] = (v4i){y1, r,  x,  y2};
    outv[2] = (v4i){r,  x,  y3, r};

    if (gid == 0u) out[INT_TOTAL] = 5;   // trailing scalar: num_relation
}

extern "C" void kernel_launch(void* const* d_in, const int* in_sizes, int n_in,
                              void* d_out, int out_size, void* d_ws, size_t ws_size,
                              hipStream_t stream) {
    const int* chain_id = (const int*)d_in[0];
    int* out = (int*)d_out;
    // E_TOTAL/4 = 5,218,304 quads; /256 = 20384 blocks exactly (no tail).
    seqedge_kernel<<<20384, 256, 0, stream>>>(chain_id, out);
}

// Round 6
// 251.977 us; speedup vs baseline: 1.0486x; 1.0486x over previous
//
#include <hip/hip_runtime.h>
#include <hip/hip_bf16.h>

// SequentialEdge: B=256, R=256, A=8, D=2.
// Output: 5 chunks (i=-2..2), chunk i = B*(R-|i|)*64 rows of [node_in, node_out, i+2],
// -1 rows where chain differs; trailing scalar 5. Total ints = 62,619,648 (+1).
//
// R6 design: persistent grid-stride version of the R1 structure (fill-kernel
// mimicry). 2548 blocks x 256 threads; each block processes 8 tiles of 256
// edge-quads (tile = bid + 2548*it -> moving contiguous 30MB window, like the
// 6.6 TB/s fillBuffer kernel). Per tile: ONE decode + ONE chain compare per
// 48B output, stage 12 ints into double-buffered swizzled LDS (1 barrier/tile),
// then 3 fully-coalesced dwordx4 store passes. Regular (cached) stores —
// nt stores (R4) and stride-48 direct stores (R5) both regressed.
//
// Chunk table (edge starts): 0 / 4,161,536 / 8,339,456 / 12,533,760 / 16,711,680
// per-graph edges: 16256 / 16320 / 16384 / 16320 / 16256. E_TOTAL = 20,873,216.
// Tiles: E_TOTAL/4/256 = 20384 = 2548 blocks * 8 iters exactly.

#define E_TOTAL   20873216u
#define INT_TOTAL 62619648u
#define NBLOCKS   2548u
#define NITER     8u

typedef int v4i __attribute__((ext_vector_type(4)));

__global__ __launch_bounds__(256)
void seqedge_kernel(const int* __restrict__ chain, int* __restrict__ out) {
    __shared__ int lds[2][3200];   // double buffer, 12.5 KB each, swizzled
    const unsigned tid = threadIdx.x;
    v4i* outv = reinterpret_cast<v4i*>(out);

    // swizzle: base(c) = 12c + 16*(c>>5) + 4*((c>>3)&3) — no overlap, b128-aligned,
    // conflict-free for both the write and the read pattern.
    const unsigned wbase = 12u * tid + 16u * (tid >> 5) + 4u * ((tid >> 3) & 3u);

    // writeout source offsets are iteration-invariant: precompute.
    unsigned pb[3], mm[3];
    #pragma unroll
    for (unsigned s = 0; s < 3; ++s) {
        const unsigned m = s * 256u + tid;
        const unsigned c = m / 3u;
        const unsigned r = m - c * 3u;
        pb[s] = 12u * c + 16u * (c >> 5) + 4u * ((c >> 3) & 3u) + 4u * r;
        mm[s] = m;
    }

    for (unsigned it = 0; it < NITER; ++it) {
        const unsigned tile = blockIdx.x + NBLOCKS * it;
        const unsigned e0   = (tile * 256u + tid) * 4u;   // first edge of this quad

        // ---- chunk decode (once per 4 edges) ----
        unsigned g, rem; int i, lo, rel;
        if (e0 < 4161536u)       { g = e0 / 16256u;                    rem = e0 - g * 16256u; i = -2; lo = 2; rel = 0; }
        else if (e0 < 8339456u)  { unsigned eo = e0 - 4161536u;  g = eo / 16320u; rem = eo - g * 16320u; i = -1; lo = 1; rel = 1; }
        else if (e0 < 12533760u) { unsigned eo = e0 - 8339456u;  g = eo >> 14;    rem = eo & 16383u;     i = 0;  lo = 0; rel = 2; }
        else if (e0 < 16711680u) { unsigned eo = e0 - 12533760u; g = eo / 16320u; rem = eo - g * 16320u; i = 1;  lo = 0; rel = 3; }
        else                     { unsigned eo = e0 - 16711680u; g = eo / 16256u; rem = eo - g * 16256u; i = 2;  lo = 0; rel = 4; }

        const unsigned rl  = (rem >> 6) + (unsigned)lo;
        const unsigned ai  = (rem >> 3) & 7u;
        const unsigned ao0 = rem & 7u;
        const int res_in  = (int)(g * 256u + rl);
        const int res_out = res_in + i;
        const bool same = chain[res_in] == chain[res_out];

        const int x  = same ? res_in * 8 + (int)ai : -1;
        const int r  = same ? rel : -1;
        const int yb = res_out * 8 + (int)ao0;
        const int y0 = same ? yb     : -1;
        const int y1 = same ? yb + 1 : -1;
        const int y2 = same ? yb + 2 : -1;
        const int y3 = same ? yb + 3 : -1;

        int* buf = lds[it & 1u];
        v4i* ldsv = reinterpret_cast<v4i*>(&buf[wbase]);
        ldsv[0] = (v4i){x,  y0, r,  x};
        ldsv[1] = (v4i){y1, r,  x,  y2};
        ldsv[2] = (v4i){r,  x,  y3, r};

        __syncthreads();   // write->read fence; buffer parity protects read->write

        const unsigned out_base = tile * 768u;
        #pragma unroll
        for (unsigned s = 0; s < 3; ++s)
            outv[out_base + mm[s]] = *reinterpret_cast<const v4i*>(&buf[pb[s]]);
    }

    if (blockIdx.x == 0u && tid == 0u) out[INT_TOTAL] = 5;   // num_relation
}

extern "C" void kernel_launch(void* const* d_in, const int* in_sizes, int n_in,
                              void* d_out, int out_size, void* d_ws, size_t ws_size,
                              hipStream_t stream) {
    const int* chain_id = (const int*)d_in[0];
    int* out = (int*)d_out;
    seqedge_kernel<<<NBLOCKS, 256, 0, stream>>>(chain_id, out);
}